// Round 1
// baseline (1044.740 us; speedup 1.0000x reference)
//
#include <hip/hip_runtime.h>
#include <hip/hip_bf16.h>
#include <cstdint>

// ---------------------------------------------------------------------------
// Fused causal self-attention block (B=2, T=2048, C=1024, H=16, Dh=64), fp32 in/out.
// Pipeline: cvt fp32->bf16 -> QKV GEMM (bf16 MFMA) -> causal flash attn -> out GEMM (fp32 out).
// Workspace layout (bytes):
//   xb    @ 0        8 MB   bf16 x            [4096][1024]
//   wqkvb @ 8  MB    6 MB   bf16 w_qkv        [3072][1024]
//   wob   @ 14 MB    2 MB   bf16 w_out        [1024][1024]
//   qkvb  @ 16 MB   24 MB   bf16 qkv          [4096][3072]  (Q | K | V per row)
//   yb    @ 40 MB    8 MB   bf16 attn output  [4096][1024]
// Total 48 MB.
// ---------------------------------------------------------------------------

typedef __bf16 bf16x8 __attribute__((ext_vector_type(8)));
typedef float  f32x4  __attribute__((ext_vector_type(4)));

#define EMB   1024
#define HEADS 16
#define HD    64
#define TT    2048
#define NROWS 4096            // B*T
#define QKVN  3072            // 3*EMB

// ---- fp32 -> bf16 (8 elems / thread) ----
__global__ void cvt_f32_bf16(const float* __restrict__ in, __bf16* __restrict__ out, int n8) {
  int i = blockIdx.x * blockDim.x + threadIdx.x;
  if (i >= n8) return;
  const float4* p = (const float4*)in + (size_t)i * 2;
  float4 a = p[0], b = p[1];
  bf16x8 o;
  o[0] = (__bf16)a.x; o[1] = (__bf16)a.y; o[2] = (__bf16)a.z; o[3] = (__bf16)a.w;
  o[4] = (__bf16)b.x; o[5] = (__bf16)b.y; o[6] = (__bf16)b.z; o[7] = (__bf16)b.w;
  *((bf16x8*)out + i) = o;
}

// ---- async global->LDS 16B (flat->AS casts via integer: LLVM lowers flat->local
//      addrspacecast as low-32-bit truncation, so this is the documented semantics) ----
__device__ __forceinline__ void gload_lds16(const void* g, void* l) {
  __builtin_amdgcn_global_load_lds(
      (const __attribute__((address_space(1))) void*)(uintptr_t)g,
      (__attribute__((address_space(3))) void*)(uint32_t)(uintptr_t)l,
      16, 0, 0);
}

// ---- GEMM: C[M,N] = A[M,K] * Bm[N,K]^T, bf16 in, fp32 acc, bf16 or fp32 out ----
// 128x128 tile, BK=32, 4 waves (2x2), each wave 64x64 = 4x4 MFMA frags.
template <int OUT_BF16>
__global__ __launch_bounds__(256, 2)
void gemm_bt(const __bf16* __restrict__ A, const __bf16* __restrict__ Bm,
             void* __restrict__ Cout, int M, int N, int K) {
  __shared__ __align__(16) __bf16 As[128 * 32];
  __shared__ __align__(16) __bf16 Bs[128 * 32];
  const int tid  = threadIdx.x;
  const int lane = tid & 63;
  const int wid  = tid >> 6;
  const int wr = wid >> 1, wc = wid & 1;
  const int brow = blockIdx.y * 128;
  const int bcol = blockIdx.x * 128;
  const int fr = lane & 15, g = lane >> 4;

  f32x4 acc[4][4];
#pragma unroll
  for (int m = 0; m < 4; m++)
#pragma unroll
    for (int n = 0; n < 4; n++)
#pragma unroll
      for (int r = 0; r < 4; r++) acc[m][n][r] = 0.0f;

  const int c0 = tid, c1 = tid + 256;   // 16B chunk ids within 8KB tile
  for (int k0 = 0; k0 < K; k0 += 32) {
    __syncthreads();
    gload_lds16(A  + (size_t)(brow + (c0 >> 2)) * K + k0 + (c0 & 3) * 8, (char*)As + c0 * 16);
    gload_lds16(A  + (size_t)(brow + (c1 >> 2)) * K + k0 + (c1 & 3) * 8, (char*)As + c1 * 16);
    gload_lds16(Bm + (size_t)(bcol + (c0 >> 2)) * K + k0 + (c0 & 3) * 8, (char*)Bs + c0 * 16);
    gload_lds16(Bm + (size_t)(bcol + (c1 >> 2)) * K + k0 + (c1 & 3) * 8, (char*)Bs + c1 * 16);
    __syncthreads();   // compiler drains vmcnt+lgkmcnt before s_barrier

    bf16x8 af[4], bfr[4];
#pragma unroll
    for (int m = 0; m < 4; m++)
      af[m] = *(const bf16x8*)((const char*)As + (wr * 64 + m * 16 + fr) * 64 + g * 16);
#pragma unroll
    for (int n = 0; n < 4; n++)
      bfr[n] = *(const bf16x8*)((const char*)Bs + (wc * 64 + n * 16 + fr) * 64 + g * 16);
#pragma unroll
    for (int m = 0; m < 4; m++)
#pragma unroll
      for (int n = 0; n < 4; n++)
        acc[m][n] = __builtin_amdgcn_mfma_f32_16x16x32_bf16(af[m], bfr[n], acc[m][n], 0, 0, 0);
  }

  // epilogue: D row = (lane>>4)*4+reg, col = lane&15
  const int rbase = brow + wr * 64 + g * 4;
  const int cbase = bcol + wc * 64 + fr;
#pragma unroll
  for (int m = 0; m < 4; m++)
#pragma unroll
    for (int n = 0; n < 4; n++) {
      const int col = cbase + n * 16;
#pragma unroll
      for (int r = 0; r < 4; r++) {
        const int row = rbase + m * 16 + r;
        const float v = acc[m][n][r];
        if (OUT_BF16) ((__bf16*)Cout)[(size_t)row * N + col] = (__bf16)v;
        else          ((float*)Cout)[(size_t)row * N + col]  = v;
      }
    }
}

// ---- XOR swizzle for 64-row x 128-byte LDS tiles (kills 128B-stride bank conflicts) ----
__device__ __forceinline__ int swzoff(int row, int bcol) {
  const int s = (((row & 7) ^ ((row >> 3) & 7))) << 4;
  return row * 128 + (bcol ^ s);
}

// ---- causal flash attention: 1 wave per block, 64 q-rows; iterate 64-kv tiles ----
// grid = (T/64, B*H). qkv: [4096][3072] bf16; yb: [4096][1024] bf16.
__global__ __launch_bounds__(64, 2)
void attn_causal(const __bf16* __restrict__ qkv, __bf16* __restrict__ yb) {
  __shared__ __align__(16) char smem[16384];   // [0,8K) P[64q][64kv], [8K,16K) Vt[64d][64kv], both swizzled
  const int lane = threadIdx.x;
  const int qt = blockIdx.x;           // q tile (64 rows)
  const int bh = blockIdx.y;
  const int b = bh >> 4, h = bh & 15;
  const size_t rowbase = (size_t)b * TT;
  const int q0 = qt * 64;
  const int fr = lane & 15, g = lane >> 4;

  // Q fragments, kept in registers for all kv tiles
  bf16x8 qf[4][2];
#pragma unroll
  for (int m = 0; m < 4; m++)
#pragma unroll
    for (int kc = 0; kc < 2; kc++)
      qf[m][kc] = *(const bf16x8*)(qkv + (rowbase + q0 + m * 16 + fr) * QKVN + h * HD + kc * 32 + g * 8);

  f32x4 o[4][4];
  float mrow[4][4], lrow[4][4];
#pragma unroll
  for (int m = 0; m < 4; m++)
#pragma unroll
    for (int n = 0; n < 4; n++) {
#pragma unroll
      for (int r = 0; r < 4; r++) o[m][n][r] = 0.0f;
      mrow[m][n] = -1e30f;  lrow[m][n] = 0.0f;   // [m][r] semantics
    }

  for (int kt = 0; kt <= qt; ++kt) {
    const int kv0 = kt * 64;
    // stage V tile transposed into LDS: Vt[d][kv]
#pragma unroll
    for (int it = 0; it < 8; ++it) {
      const int row = it * 8 + (lane >> 3);        // kv local
      const int dch = (lane & 7) * 8;              // d base
      bf16x8 v = *(const bf16x8*)(qkv + (rowbase + kv0 + row) * QKVN + 2 * EMB + h * HD + dch);
#pragma unroll
      for (int j = 0; j < 8; j++)
        *(__bf16*)(smem + 8192 + swzoff(dch + j, row * 2)) = v[j];
    }
    // K fragments straight from global (L2-resident)
    bf16x8 kf[4][2];
#pragma unroll
    for (int n = 0; n < 4; n++)
#pragma unroll
      for (int kc = 0; kc < 2; kc++)
        kf[n][kc] = *(const bf16x8*)(qkv + (rowbase + kv0 + n * 16 + fr) * QKVN + EMB + h * HD + kc * 32 + g * 8);

    // S = Q K^T  (S[q][kv], D-layout)
    f32x4 s[4][4];
#pragma unroll
    for (int m = 0; m < 4; m++)
#pragma unroll
      for (int n = 0; n < 4; n++) {
#pragma unroll
        for (int r = 0; r < 4; r++) s[m][n][r] = 0.0f;
#pragma unroll
        for (int kc = 0; kc < 2; kc++)
          s[m][n] = __builtin_amdgcn_mfma_f32_16x16x32_bf16(qf[m][kc], kf[n][kc], s[m][n], 0, 0, 0);
      }
    // scale + causal mask
    const bool diag = (kt == qt);
#pragma unroll
    for (int m = 0; m < 4; m++)
#pragma unroll
      for (int n = 0; n < 4; n++)
#pragma unroll
        for (int r = 0; r < 4; r++) {
          float val = s[m][n][r] * 0.125f;
          if (diag) {
            const int qloc = m * 16 + g * 4 + r, kloc = n * 16 + fr;
            if (kloc > qloc) val = -1e30f;
          }
          s[m][n][r] = val;
        }
    // online softmax per row (row = m*16 + g*4 + r; 16 lanes of a group share a row)
#pragma unroll
    for (int m = 0; m < 4; m++)
#pragma unroll
      for (int r = 0; r < 4; r++) {
        float pm = s[m][0][r];
#pragma unroll
        for (int n = 1; n < 4; n++) pm = fmaxf(pm, s[m][n][r]);
#pragma unroll
        for (int d = 1; d < 16; d <<= 1) pm = fmaxf(pm, __shfl_xor(pm, d, 64));
        const float mn = fmaxf(mrow[m][r], pm);
        const float f = __expf(mrow[m][r] - mn);
        mrow[m][r] = mn;
        lrow[m][r] *= f;
#pragma unroll
        for (int n = 0; n < 4; n++) o[m][n][r] *= f;
        float rs = 0.0f;
#pragma unroll
        for (int n = 0; n < 4; n++) {
          const float e = __expf(s[m][n][r] - mn);
          s[m][n][r] = e;  rs += e;
        }
#pragma unroll
        for (int d = 1; d < 16; d <<= 1) rs += __shfl_xor(rs, d, 64);
        lrow[m][r] += rs;
      }
    // P -> LDS (bf16, swizzled), then PV MFMA
#pragma unroll
    for (int m = 0; m < 4; m++)
#pragma unroll
      for (int n = 0; n < 4; n++)
#pragma unroll
        for (int r = 0; r < 4; r++)
          *(__bf16*)(smem + swzoff(m * 16 + g * 4 + r, (n * 16 + fr) * 2)) = (__bf16)s[m][n][r];

    bf16x8 pa[4][2], vb[4][2];
#pragma unroll
    for (int m = 0; m < 4; m++)
#pragma unroll
      for (int kc = 0; kc < 2; kc++)
        pa[m][kc] = *(const bf16x8*)(smem + swzoff(m * 16 + fr, kc * 64 + g * 16));
#pragma unroll
    for (int n = 0; n < 4; n++)
#pragma unroll
      for (int kc = 0; kc < 2; kc++)
        vb[n][kc] = *(const bf16x8*)(smem + 8192 + swzoff(n * 16 + fr, kc * 64 + g * 16));
#pragma unroll
    for (int m = 0; m < 4; m++)
#pragma unroll
      for (int n = 0; n < 4; n++)
#pragma unroll
        for (int kc = 0; kc < 2; kc++)
          o[m][n] = __builtin_amdgcn_mfma_f32_16x16x32_bf16(pa[m][kc], vb[n][kc], o[m][n], 0, 0, 0);
  }

  // normalize + store y (bf16)
#pragma unroll
  for (int m = 0; m < 4; m++)
#pragma unroll
    for (int n = 0; n < 4; n++)
#pragma unroll
      for (int r = 0; r < 4; r++) {
        const int q = q0 + m * 16 + g * 4 + r;
        const int d = n * 16 + fr;
        yb[(rowbase + q) * EMB + h * HD + d] = (__bf16)(o[m][n][r] / lrow[m][r]);
      }
}

extern "C" void kernel_launch(void* const* d_in, const int* in_sizes, int n_in,
                              void* d_out, int out_size, void* d_ws, size_t ws_size,
                              hipStream_t stream) {
  const float* x     = (const float*)d_in[0];
  const float* w_qkv = (const float*)d_in[1];
  const float* w_out = (const float*)d_in[2];
  float* out = (float*)d_out;

  char* ws = (char*)d_ws;
  __bf16* xb    = (__bf16*)(ws);
  __bf16* wqkvb = (__bf16*)(ws + (8ull  << 20));
  __bf16* wob   = (__bf16*)(ws + (14ull << 20));
  __bf16* qkvb  = (__bf16*)(ws + (16ull << 20));
  __bf16* yb    = (__bf16*)(ws + (40ull << 20));

  // fp32 -> bf16
  cvt_f32_bf16<<<2048, 256, 0, stream>>>(x,     xb,    524288);
  cvt_f32_bf16<<<1536, 256, 0, stream>>>(w_qkv, wqkvb, 393216);
  cvt_f32_bf16<<<512,  256, 0, stream>>>(w_out, wob,   131072);
  // QKV projection: [4096,3072] bf16
  gemm_bt<1><<<dim3(QKVN / 128, NROWS / 128), 256, 0, stream>>>(xb, wqkvb, qkvb, NROWS, QKVN, EMB);
  // causal attention -> yb [4096,1024] bf16
  attn_causal<<<dim3(TT / 64, 2 * HEADS), 64, 0, stream>>>(qkvb, yb);
  // output projection -> fp32 d_out
  gemm_bt<0><<<dim3(EMB / 128, NROWS / 128), 256, 0, stream>>>(yb, wob, out, NROWS, EMB, EMB);
}

// Round 2
// 171.622 us; speedup vs baseline: 6.0875x; 6.0875x over previous
//
#include <hip/hip_runtime.h>
#include <hip/hip_bf16.h>
#include <cstdint>

// ---------------------------------------------------------------------------
// Fused causal self-attention block (B=2, T=2048, C=1024, H=16, Dh=64), fp32 in/out.
// Pipeline: cvt fp32->bf16 -> QKV GEMM (bf16 MFMA) -> causal flash attn -> out GEMM (fp32 out).
// Workspace layout (bytes):
//   xb    @ 0        8 MB   bf16 x            [4096][1024]
//   wqkvb @ 8  MB    6 MB   bf16 w_qkv        [3072][1024]
//   wob   @ 14 MB    2 MB   bf16 w_out        [1024][1024]
//   qkvb  @ 16 MB   24 MB   bf16 qkv          [4096][3072]  (Q | K | V per row)
//   yb    @ 40 MB    8 MB   bf16 attn output  [4096][1024]
// ---------------------------------------------------------------------------

typedef __bf16 bf16x8 __attribute__((ext_vector_type(8)));
typedef float  f32x4  __attribute__((ext_vector_type(4)));

#define EMB   1024
#define HEADS 16
#define HD    64
#define TT    2048
#define NROWS 4096
#define QKVN  3072

// ---- fp32 -> bf16 (8 elems / thread) ----
__global__ void cvt_f32_bf16(const float* __restrict__ in, __bf16* __restrict__ out, int n8) {
  int i = blockIdx.x * blockDim.x + threadIdx.x;
  if (i >= n8) return;
  const float4* p = (const float4*)in + (size_t)i * 2;
  float4 a = p[0], b = p[1];
  bf16x8 o;
  o[0] = (__bf16)a.x; o[1] = (__bf16)a.y; o[2] = (__bf16)a.z; o[3] = (__bf16)a.w;
  o[4] = (__bf16)b.x; o[5] = (__bf16)b.y; o[6] = (__bf16)b.z; o[7] = (__bf16)b.w;
  *((bf16x8*)out + i) = o;
}

__device__ __forceinline__ void gload_lds16(const void* g, void* l) {
  __builtin_amdgcn_global_load_lds(
      (const __attribute__((address_space(1))) void*)(uintptr_t)g,
      (__attribute__((address_space(3))) void*)(uint32_t)(uintptr_t)l,
      16, 0, 0);
}

// ---- GEMM: C[M,N] = A[M,K] * Bm[N,K]^T (m97 structure, unchanged from R1) ----
template <int OUT_BF16>
__global__ __launch_bounds__(256, 2)
void gemm_bt(const __bf16* __restrict__ A, const __bf16* __restrict__ Bm,
             void* __restrict__ Cout, int M, int N, int K) {
  __shared__ __align__(16) __bf16 As[128 * 32];
  __shared__ __align__(16) __bf16 Bs[128 * 32];
  const int tid  = threadIdx.x;
  const int lane = tid & 63;
  const int wid  = tid >> 6;
  const int wr = wid >> 1, wc = wid & 1;
  const int brow = blockIdx.y * 128;
  const int bcol = blockIdx.x * 128;
  const int fr = lane & 15, g = lane >> 4;

  f32x4 acc[4][4];
#pragma unroll
  for (int m = 0; m < 4; m++)
#pragma unroll
    for (int n = 0; n < 4; n++)
#pragma unroll
      for (int r = 0; r < 4; r++) acc[m][n][r] = 0.0f;

  const int c0 = tid, c1 = tid + 256;
  for (int k0 = 0; k0 < K; k0 += 32) {
    __syncthreads();
    gload_lds16(A  + (size_t)(brow + (c0 >> 2)) * K + k0 + (c0 & 3) * 8, (char*)As + c0 * 16);
    gload_lds16(A  + (size_t)(brow + (c1 >> 2)) * K + k0 + (c1 & 3) * 8, (char*)As + c1 * 16);
    gload_lds16(Bm + (size_t)(bcol + (c0 >> 2)) * K + k0 + (c0 & 3) * 8, (char*)Bs + c0 * 16);
    gload_lds16(Bm + (size_t)(bcol + (c1 >> 2)) * K + k0 + (c1 & 3) * 8, (char*)Bs + c1 * 16);
    __syncthreads();

    bf16x8 af[4], bfr[4];
#pragma unroll
    for (int m = 0; m < 4; m++)
      af[m] = *(const bf16x8*)((const char*)As + (wr * 64 + m * 16 + fr) * 64 + g * 16);
#pragma unroll
    for (int n = 0; n < 4; n++)
      bfr[n] = *(const bf16x8*)((const char*)Bs + (wc * 64 + n * 16 + fr) * 64 + g * 16);
#pragma unroll
    for (int m = 0; m < 4; m++)
#pragma unroll
      for (int n = 0; n < 4; n++)
        acc[m][n] = __builtin_amdgcn_mfma_f32_16x16x32_bf16(af[m], bfr[n], acc[m][n], 0, 0, 0);
  }

  const int rbase = brow + wr * 64 + g * 4;
  const int cbase = bcol + wc * 64 + fr;
#pragma unroll
  for (int m = 0; m < 4; m++)
#pragma unroll
    for (int n = 0; n < 4; n++) {
      const int col = cbase + n * 16;
#pragma unroll
      for (int r = 0; r < 4; r++) {
        const int row = rbase + m * 16 + r;
        const float v = acc[m][n][r];
        if (OUT_BF16) ((__bf16*)Cout)[(size_t)row * N + col] = (__bf16)v;
        else          ((float*)Cout)[(size_t)row * N + col]  = v;
      }
    }
}

// ---------------------------------------------------------------------------
// Causal flash attention v2: 4 waves/block, wave owns 32 q rows, block 128.
// K double-buffered via source-swizzled global_load_lds (linear dest).
// V reg-staged, written transposed+swizzled (Vt[d][kv]) after barrier (T14).
// Fold-balanced chunks: blocks pairing on a CU sum to constant work.
// grid.x = 512: L -> bh = L&31 (XCD = bh%8 -> L2 locality), p = L>>5,
//               chunk = p<8 ? p : 23-p.
// ---------------------------------------------------------------------------
__device__ __forceinline__ int psw(int row) {           // P-buffer swizzle (v1)
  return (((row & 7) ^ ((row >> 3) & 7))) << 4;
}

__global__ __launch_bounds__(256, 2)
void attn_causal2(const __bf16* __restrict__ qkv, __bf16* __restrict__ yb) {
  __shared__ __align__(16) char Kbuf[2][8192];   // K[row=kv][d], chunk-swizzled: pos = c16 ^ (row&7)
  __shared__ __align__(16) char Vbuf[2][8192];   // Vt[d][kv], chunk-swizzled: pos = kv16 ^ (d&7) ^ ((d>>3)&7)
  __shared__ __align__(16) char Pbuf[4][4096];   // per-wave P[32][64], psw-swizzled

  const int tid = threadIdx.x;
  const int lane = tid & 63, w = tid >> 6;
  const int L = blockIdx.x;
  const int bh = L & 31, p = L >> 5;
  const int chunk = (p < 8) ? p : 23 - p;
  const int b = bh >> 4, h = bh & 15;
  const size_t rowbase = (size_t)b * TT;
  const int q0 = chunk * 128 + w * 32;           // wave's first q row
  const int fr = lane & 15, g = lane >> 4;
  const int ntiles = 2 * chunk + 2;

  // Q fragments (2 m-frags x 2 k-chunks), resident all tiles
  bf16x8 qf[2][2];
#pragma unroll
  for (int m = 0; m < 2; m++)
#pragma unroll
    for (int kc = 0; kc < 2; kc++)
      qf[m][kc] = *(const bf16x8*)(qkv + (rowbase + q0 + m * 16 + fr) * QKVN + h * HD + kc * 32 + g * 8);

  f32x4 o[2][4];
  float mrow[2][4], lrow[2][4];
#pragma unroll
  for (int m = 0; m < 2; m++)
#pragma unroll
    for (int n = 0; n < 4; n++) {
#pragma unroll
      for (int r = 0; r < 4; r++) o[m][n][r] = 0.0f;
      mrow[m][n] = -1e30f;  lrow[m][n] = 0.0f;
    }

  // --- staging helpers (block-cooperative, 512 16B-chunks per 8KB tile) ---
  auto stageK = [&](int kt, int buf) {
#pragma unroll
    for (int i = 0; i < 2; i++) {
      const int c = tid + i * 256;
      const int row = c >> 3;
      const int c16 = (c & 7) ^ (row & 7);       // source pre-swizzle (dest stays linear)
      gload_lds16(qkv + (rowbase + kt * 64 + row) * QKVN + EMB + h * HD + c16 * 8,
                  Kbuf[buf] + c * 16);
    }
  };
  auto loadV = [&](int kt, bf16x8 vr[2]) {
#pragma unroll
    for (int i = 0; i < 2; i++) {
      const int c = tid + i * 256;
      const int row = c >> 3, d16 = c & 7;
      vr[i] = *(const bf16x8*)(qkv + (rowbase + kt * 64 + row) * QKVN + 2 * EMB + h * HD + d16 * 8);
    }
  };
  auto writeV = [&](bf16x8 vr[2], int buf) {
#pragma unroll
    for (int i = 0; i < 2; i++) {
      const int c = tid + i * 256;
      const int kv = c >> 3, dch = (c & 7) * 8;
#pragma unroll
      for (int j = 0; j < 8; j++) {
        const int d = dch + j;
        const int sw = (d & 7) ^ ((d >> 3) & 7);
        const int byte = d * 128 + (((kv >> 3) ^ sw) * 8 + (kv & 7)) * 2;
        *(__bf16*)(Vbuf[buf] + byte) = vr[i][j];
      }
    }
  };

  // --- prologue: tile 0 ---
  bf16x8 vr[2], vrn[2];
  stageK(0, 0);
  loadV(0, vr);
  __syncthreads();                 // drains vmcnt: K tile 0 in LDS, V in regs
  writeV(vr, 0);
  __syncthreads();                 // Vt tile 0 visible

  int cur = 0;
  for (int kt = 0; kt < ntiles; kt++) {
    const bool have_next = (kt + 1 < ntiles);
    if (have_next) { stageK(kt + 1, cur ^ 1); loadV(kt + 1, vrn); }   // issue early (T14)

    const int kv0 = kt * 64;
    if (kv0 <= q0 + 31) {          // this wave has work in this tile
      // K fragments from swizzled LDS
      bf16x8 kf[4][2];
#pragma unroll
      for (int n = 0; n < 4; n++)
#pragma unroll
        for (int kc = 0; kc < 2; kc++) {
          const int row = n * 16 + fr;
          kf[n][kc] = *(const bf16x8*)(Kbuf[cur] + row * 128 + (((kc << 2) | g) ^ (row & 7)) * 16);
        }
      // S = Q K^T
      f32x4 s[2][4];
#pragma unroll
      for (int m = 0; m < 2; m++)
#pragma unroll
        for (int n = 0; n < 4; n++) {
#pragma unroll
          for (int r = 0; r < 4; r++) s[m][n][r] = 0.0f;
#pragma unroll
          for (int kc = 0; kc < 2; kc++)
            s[m][n] = __builtin_amdgcn_mfma_f32_16x16x32_bf16(qf[m][kc], kf[n][kc], s[m][n], 0, 0, 0);
        }
      // scale + causal mask
      const bool domask = (kv0 + 63 > q0);
#pragma unroll
      for (int m = 0; m < 2; m++)
#pragma unroll
        for (int n = 0; n < 4; n++)
#pragma unroll
          for (int r = 0; r < 4; r++) {
            float val = s[m][n][r] * 0.125f;
            if (domask) {
              const int qg = q0 + m * 16 + g * 4 + r;
              const int kg = kv0 + n * 16 + fr;
              if (kg > qg) val = -1e30f;
            }
            s[m][n][r] = val;
          }
      // online softmax (row = m*16+g*4+r; 16 lanes share a row)
#pragma unroll
      for (int m = 0; m < 2; m++)
#pragma unroll
        for (int r = 0; r < 4; r++) {
          float pm = fmaxf(fmaxf(s[m][0][r], s[m][1][r]), fmaxf(s[m][2][r], s[m][3][r]));
#pragma unroll
          for (int d = 1; d < 16; d <<= 1) pm = fmaxf(pm, __shfl_xor(pm, d, 64));
          const float mn = fmaxf(mrow[m][r], pm);
          const float f = __expf(mrow[m][r] - mn);
          mrow[m][r] = mn;
          lrow[m][r] *= f;
#pragma unroll
          for (int n = 0; n < 4; n++) o[m][n][r] *= f;
          float rs = 0.0f;
#pragma unroll
          for (int n = 0; n < 4; n++) {
            const float e = __expf(s[m][n][r] - mn);
            s[m][n][r] = e;  rs += e;
          }
#pragma unroll
          for (int d = 1; d < 16; d <<= 1) rs += __shfl_xor(rs, d, 64);
          lrow[m][r] += rs;
        }
      // P -> wave-private LDS (swizzled)
#pragma unroll
      for (int m = 0; m < 2; m++)
#pragma unroll
        for (int n = 0; n < 4; n++)
#pragma unroll
          for (int r = 0; r < 4; r++) {
            const int row = m * 16 + g * 4 + r;
            *(__bf16*)(Pbuf[w] + row * 128 + (((n * 16 + fr) * 2) ^ psw(row))) = (__bf16)s[m][n][r];
          }
      // PV
      bf16x8 pa[2][2], vb[4][2];
#pragma unroll
      for (int m = 0; m < 2; m++)
#pragma unroll
        for (int kc = 0; kc < 2; kc++) {
          const int row = m * 16 + fr;
          pa[m][kc] = *(const bf16x8*)(Pbuf[w] + row * 128 + ((kc * 64 + g * 16) ^ psw(row)));
        }
#pragma unroll
      for (int n = 0; n < 4; n++)
#pragma unroll
        for (int kc = 0; kc < 2; kc++) {
          const int d = n * 16 + fr;
          const int sw = (d & 7) ^ ((d >> 3) & 7);
          vb[n][kc] = *(const bf16x8*)(Vbuf[cur] + d * 128 + (((kc << 2) | g) ^ sw) * 16);
        }
#pragma unroll
      for (int m = 0; m < 2; m++)
#pragma unroll
        for (int n = 0; n < 4; n++)
#pragma unroll
          for (int kc = 0; kc < 2; kc++)
            o[m][n] = __builtin_amdgcn_mfma_f32_16x16x32_bf16(pa[m][kc], vb[n][kc], o[m][n], 0, 0, 0);
    }

    __syncthreads();               // all waves done with cur; next K-tile DMA drained
    if (have_next) writeV(vrn, cur ^ 1);
    __syncthreads();               // next Vt visible
    cur ^= 1;
  }

  // normalize + store
#pragma unroll
  for (int m = 0; m < 2; m++)
#pragma unroll
    for (int n = 0; n < 4; n++)
#pragma unroll
      for (int r = 0; r < 4; r++) {
        const int q = q0 + m * 16 + g * 4 + r;
        const int d = n * 16 + fr;
        yb[(rowbase + q) * EMB + h * HD + d] = (__bf16)(o[m][n][r] / lrow[m][r]);
      }
}

extern "C" void kernel_launch(void* const* d_in, const int* in_sizes, int n_in,
                              void* d_out, int out_size, void* d_ws, size_t ws_size,
                              hipStream_t stream) {
  const float* x     = (const float*)d_in[0];
  const float* w_qkv = (const float*)d_in[1];
  const float* w_out = (const float*)d_in[2];
  float* out = (float*)d_out;

  char* ws = (char*)d_ws;
  __bf16* xb    = (__bf16*)(ws);
  __bf16* wqkvb = (__bf16*)(ws + (8ull  << 20));
  __bf16* wob   = (__bf16*)(ws + (14ull << 20));
  __bf16* qkvb  = (__bf16*)(ws + (16ull << 20));
  __bf16* yb    = (__bf16*)(ws + (40ull << 20));

  cvt_f32_bf16<<<2048, 256, 0, stream>>>(x,     xb,    524288);
  cvt_f32_bf16<<<1536, 256, 0, stream>>>(w_qkv, wqkvb, 393216);
  cvt_f32_bf16<<<512,  256, 0, stream>>>(w_out, wob,   131072);
  gemm_bt<1><<<dim3(QKVN / 128, NROWS / 128), 256, 0, stream>>>(xb, wqkvb, qkvb, NROWS, QKVN, EMB);
  attn_causal2<<<512, 256, 0, stream>>>(qkvb, yb);
  gemm_bt<0><<<dim3(EMB / 128, NROWS / 128), 256, 0, stream>>>(yb, wob, out, NROWS, EMB, EMB);
}

// Round 3
// 118.873 us; speedup vs baseline: 8.7887x; 1.4437x over previous
//
#include <hip/hip_runtime.h>
#include <hip/hip_bf16.h>
#include <cstdint>

// ---------------------------------------------------------------------------
// Fused causal self-attention block (B=2, T=2048, C=1024, H=16, Dh=64), fp32 in/out.
// cvt fp32->bf16 -> QKV GEMM (bf16 MFMA) -> causal flash attn -> out GEMM (fp32).
// Workspace: xb@0 (8MB) | wqkvb@8M (6MB) | wob@14M (2MB) | qkvb@16M (24MB) | yb@40M (8MB)
// ---------------------------------------------------------------------------

typedef __bf16 bf16x8 __attribute__((ext_vector_type(8)));
typedef float  f32x4  __attribute__((ext_vector_type(4)));

#define EMB   1024
#define HEADS 16
#define HD    64
#define TT    2048
#define NROWS 4096
#define QKVN  3072

// ---- fp32 -> bf16 (8 elems / thread) ----
__global__ void cvt_f32_bf16(const float* __restrict__ in, __bf16* __restrict__ out, int n8) {
  int i = blockIdx.x * blockDim.x + threadIdx.x;
  if (i >= n8) return;
  const float4* p = (const float4*)in + (size_t)i * 2;
  float4 a = p[0], b = p[1];
  bf16x8 o;
  o[0] = (__bf16)a.x; o[1] = (__bf16)a.y; o[2] = (__bf16)a.z; o[3] = (__bf16)a.w;
  o[4] = (__bf16)b.x; o[5] = (__bf16)b.y; o[6] = (__bf16)b.z; o[7] = (__bf16)b.w;
  *((bf16x8*)out + i) = o;
}

__device__ __forceinline__ void gload_lds16(const void* g, void* l) {
  __builtin_amdgcn_global_load_lds(
      (const __attribute__((address_space(1))) void*)(uintptr_t)g,
      (__attribute__((address_space(3))) void*)(uint32_t)(uintptr_t)l,
      16, 0, 0);
}

// ---- GEMM: C[M,N] = A[M,K] * Bm[N,K]^T (m97 structure) + bijective XCD swizzle ----
template <int OUT_BF16>
__global__ __launch_bounds__(256, 2)
void gemm_bt(const __bf16* __restrict__ A, const __bf16* __restrict__ Bm,
             void* __restrict__ Cout, int M, int N, int K) {
  __shared__ __align__(16) __bf16 As[128 * 32];
  __shared__ __align__(16) __bf16 Bs[128 * 32];
  const int tid  = threadIdx.x;
  const int lane = tid & 63;
  const int wid  = tid >> 6;
  const int wr = wid >> 1, wc = wid & 1;
  // XCD-aware bijective remap (nwg % 8 == 0 for all our launches)
  const int nwg = gridDim.x * gridDim.y;
  int flat = blockIdx.y * gridDim.x + blockIdx.x;
  flat = (flat & 7) * (nwg >> 3) + (flat >> 3);
  const int brow = (flat / gridDim.x) * 128;
  const int bcol = (flat % gridDim.x) * 128;
  const int fr = lane & 15, g = lane >> 4;

  f32x4 acc[4][4];
#pragma unroll
  for (int m = 0; m < 4; m++)
#pragma unroll
    for (int n = 0; n < 4; n++)
#pragma unroll
      for (int r = 0; r < 4; r++) acc[m][n][r] = 0.0f;

  const int c0 = tid, c1 = tid + 256;
  for (int k0 = 0; k0 < K; k0 += 32) {
    __syncthreads();
    gload_lds16(A  + (size_t)(brow + (c0 >> 2)) * K + k0 + (c0 & 3) * 8, (char*)As + c0 * 16);
    gload_lds16(A  + (size_t)(brow + (c1 >> 2)) * K + k0 + (c1 & 3) * 8, (char*)As + c1 * 16);
    gload_lds16(Bm + (size_t)(bcol + (c0 >> 2)) * K + k0 + (c0 & 3) * 8, (char*)Bs + c0 * 16);
    gload_lds16(Bm + (size_t)(bcol + (c1 >> 2)) * K + k0 + (c1 & 3) * 8, (char*)Bs + c1 * 16);
    __syncthreads();

    bf16x8 af[4], bfr[4];
#pragma unroll
    for (int m = 0; m < 4; m++)
      af[m] = *(const bf16x8*)((const char*)As + (wr * 64 + m * 16 + fr) * 64 + g * 16);
#pragma unroll
    for (int n = 0; n < 4; n++)
      bfr[n] = *(const bf16x8*)((const char*)Bs + (wc * 64 + n * 16 + fr) * 64 + g * 16);
#pragma unroll
    for (int m = 0; m < 4; m++)
#pragma unroll
      for (int n = 0; n < 4; n++)
        acc[m][n] = __builtin_amdgcn_mfma_f32_16x16x32_bf16(af[m], bfr[n], acc[m][n], 0, 0, 0);
  }

  const int rbase = brow + wr * 64 + g * 4;
  const int cbase = bcol + wc * 64 + fr;
#pragma unroll
  for (int m = 0; m < 4; m++)
#pragma unroll
    for (int n = 0; n < 4; n++) {
      const int col = cbase + n * 16;
#pragma unroll
      for (int r = 0; r < 4; r++) {
        const int row = rbase + m * 16 + r;
        const float v = acc[m][n][r];
        if (OUT_BF16) ((__bf16*)Cout)[(size_t)row * N + col] = (__bf16)v;
        else          ((float*)Cout)[(size_t)row * N + col]  = v;
      }
    }
}

// ---------------------------------------------------------------------------
// Causal flash attention v3: 4 waves/block, wave owns 16 q rows (QBLK=64).
// grid = 1024 (32 chunks x 32 bh): 4 blocks/CU all-resident, 16 waves/CU.
// Defer-max vote softmax (T13), row-sum via ones-MFMA (no sum shuffles).
// K double-buffered gload_lds (source-swizzled); V reg-staged -> swizzled Vt.
// ---------------------------------------------------------------------------
__device__ __forceinline__ int psw(int row) {
  return (((row & 7) ^ ((row >> 3) & 7))) << 4;
}

__global__ __launch_bounds__(256, 4)
void attn_causal3(const __bf16* __restrict__ qkv, __bf16* __restrict__ yb) {
  __shared__ __align__(16) char Kbuf[2][8192];   // K[kv][d], chunk-swizzled
  __shared__ __align__(16) char Vbuf[2][8192];   // Vt[d][kv], chunk-swizzled
  __shared__ __align__(16) char Pbuf[4][2048];   // per-wave P[16][64], psw-swizzled

  const int tid = threadIdx.x;
  const int lane = tid & 63, w = tid >> 6;
  const int L = blockIdx.x;
  const int bh = L & 31, p = L >> 5;
  const int chunk = (p < 16) ? p : 47 - p;       // fold-balanced: pairs sum to 31
  const int b = bh >> 4, h = bh & 15;
  const size_t rowbase = (size_t)b * TT;
  const int q0 = chunk * 64 + w * 16;            // wave's first q row
  const int fr = lane & 15, g = lane >> 4;
  const int ntiles = chunk + 1;

  // Q fragments (1 m-frag x 2 k-chunks)
  bf16x8 qf[2];
#pragma unroll
  for (int kc = 0; kc < 2; kc++)
    qf[kc] = *(const bf16x8*)(qkv + (rowbase + q0 + fr) * QKVN + h * HD + kc * 32 + g * 8);

  bf16x8 ones;
#pragma unroll
  for (int j = 0; j < 8; j++) ones[j] = (__bf16)1.0f;

  f32x4 o[4];                                    // O accumulators [n][r]
  f32x4 lacc;                                    // row-sum accumulator (ones-MFMA)
  float m[4];                                    // running max per r (row = g*4+r)
#pragma unroll
  for (int n = 0; n < 4; n++)
#pragma unroll
    for (int r = 0; r < 4; r++) o[n][r] = 0.0f;
#pragma unroll
  for (int r = 0; r < 4; r++) { lacc[r] = 0.0f; m[r] = -1e30f; }

  // --- staging helpers (block-cooperative, 512 16B-chunks per 8KB tile) ---
  auto stageK = [&](int kt, int buf) {
#pragma unroll
    for (int i = 0; i < 2; i++) {
      const int c = tid + i * 256;
      const int row = c >> 3;
      const int c16 = (c & 7) ^ (row & 7);       // source pre-swizzle, linear dest
      gload_lds16(qkv + (rowbase + kt * 64 + row) * QKVN + EMB + h * HD + c16 * 8,
                  Kbuf[buf] + c * 16);
    }
  };
  auto loadV = [&](int kt, bf16x8 vr[2]) {
#pragma unroll
    for (int i = 0; i < 2; i++) {
      const int c = tid + i * 256;
      const int row = c >> 3, d16 = c & 7;
      vr[i] = *(const bf16x8*)(qkv + (rowbase + kt * 64 + row) * QKVN + 2 * EMB + h * HD + d16 * 8);
    }
  };
  auto writeV = [&](bf16x8 vr[2], int buf) {
#pragma unroll
    for (int i = 0; i < 2; i++) {
      const int c = tid + i * 256;
      const int kv = c >> 3, dch = (c & 7) * 8;
#pragma unroll
      for (int j = 0; j < 8; j++) {
        const int d = dch + j;
        const int sw = (d & 7) ^ ((d >> 3) & 7);
        const int byte = d * 128 + (((kv >> 3) ^ sw) * 8 + (kv & 7)) * 2;
        *(__bf16*)(Vbuf[buf] + byte) = vr[i][j];
      }
    }
  };

  // --- prologue ---
  bf16x8 vr[2], vrn[2];
  stageK(0, 0);
  loadV(0, vr);
  __syncthreads();
  writeV(vr, 0);
  __syncthreads();

  int cur = 0;
  for (int kt = 0; kt < ntiles; kt++) {
    const bool have_next = (kt + 1 < ntiles);
    if (have_next) { stageK(kt + 1, cur ^ 1); loadV(kt + 1, vrn); }   // issue early (T14)

    const int kv0 = kt * 64;
    // K fragments from swizzled LDS
    bf16x8 kf[4][2];
#pragma unroll
    for (int n = 0; n < 4; n++)
#pragma unroll
      for (int kc = 0; kc < 2; kc++) {
        const int row = n * 16 + fr;
        kf[n][kc] = *(const bf16x8*)(Kbuf[cur] + row * 128 + (((kc << 2) | g) ^ (row & 7)) * 16);
      }
    // S = Q K^T
    f32x4 s[4];
#pragma unroll
    for (int n = 0; n < 4; n++) {
#pragma unroll
      for (int r = 0; r < 4; r++) s[n][r] = 0.0f;
#pragma unroll
      for (int kc = 0; kc < 2; kc++)
        s[n] = __builtin_amdgcn_mfma_f32_16x16x32_bf16(qf[kc], kf[n][kc], s[n], 0, 0, 0);
    }
    // scale + causal mask (only the diagonal tile needs masking)
    if (kt == chunk) {
#pragma unroll
      for (int n = 0; n < 4; n++)
#pragma unroll
        for (int r = 0; r < 4; r++) {
          float val = s[n][r] * 0.125f;
          const int qg = q0 + g * 4 + r;
          const int kg = kv0 + n * 16 + fr;
          s[n][r] = (kg > qg) ? -1e30f : val;
        }
    } else {
#pragma unroll
      for (int n = 0; n < 4; n++)
#pragma unroll
        for (int r = 0; r < 4; r++) s[n][r] *= 0.125f;
    }
    // defer-max vote softmax
    float pm[4];
#pragma unroll
    for (int r = 0; r < 4; r++)
      pm[r] = fmaxf(fmaxf(s[0][r], s[1][r]), fmaxf(s[2][r], s[3][r]));
    const bool ok = (pm[0] <= m[0] + 8.0f) && (pm[1] <= m[1] + 8.0f) &&
                    (pm[2] <= m[2] + 8.0f) && (pm[3] <= m[3] + 8.0f);
    if (!__all(ok)) {
      // rescale path (tile 0 + rare max growth)
#pragma unroll
      for (int r = 0; r < 4; r++) {
        float rm = pm[r];
#pragma unroll
        for (int d = 1; d < 16; d <<= 1) rm = fmaxf(rm, __shfl_xor(rm, d, 16));
        const float nm = fmaxf(m[r], rm);
        const float f = __expf(m[r] - nm);
        m[r] = nm;
        lacc[r] *= f;
#pragma unroll
        for (int n = 0; n < 4; n++) o[n][r] *= f;
      }
    }
    // P = exp(S - m) -> wave-private LDS (bf16, swizzled)
#pragma unroll
    for (int n = 0; n < 4; n++)
#pragma unroll
      for (int r = 0; r < 4; r++) {
        const float e = __expf(s[n][r] - m[r]);
        const int row = g * 4 + r;
        *(__bf16*)(Pbuf[w] + row * 128 + (((n * 16 + fr) * 2) ^ psw(row))) = (__bf16)e;
      }
    // PV + row-sum via ones-MFMA
    bf16x8 pa[2];
#pragma unroll
    for (int kc = 0; kc < 2; kc++)
      pa[kc] = *(const bf16x8*)(Pbuf[w] + fr * 128 + ((kc * 64 + g * 16) ^ psw(fr)));
    bf16x8 vb[4][2];
#pragma unroll
    for (int n = 0; n < 4; n++)
#pragma unroll
      for (int kc = 0; kc < 2; kc++) {
        const int d = n * 16 + fr;
        const int sw = (d & 7) ^ ((d >> 3) & 7);
        vb[n][kc] = *(const bf16x8*)(Vbuf[cur] + d * 128 + (((kc << 2) | g) ^ sw) * 16);
      }
#pragma unroll
    for (int kc = 0; kc < 2; kc++) {
      lacc = __builtin_amdgcn_mfma_f32_16x16x32_bf16(pa[kc], ones, lacc, 0, 0, 0);
#pragma unroll
      for (int n = 0; n < 4; n++)
        o[n] = __builtin_amdgcn_mfma_f32_16x16x32_bf16(pa[kc], vb[n][kc], o[n], 0, 0, 0);
    }

    __syncthreads();               // waves done with cur; next K-tile DMA drained
    if (have_next) writeV(vrn, cur ^ 1);
    __syncthreads();               // next Vt visible
    cur ^= 1;
  }

  // normalize + store (row = g*4+r, col = n*16+fr)
#pragma unroll
  for (int n = 0; n < 4; n++)
#pragma unroll
    for (int r = 0; r < 4; r++) {
      const int q = q0 + g * 4 + r;
      const int d = n * 16 + fr;
      yb[(rowbase + q) * EMB + h * HD + d] = (__bf16)(o[n][r] / lacc[r]);
    }
}

extern "C" void kernel_launch(void* const* d_in, const int* in_sizes, int n_in,
                              void* d_out, int out_size, void* d_ws, size_t ws_size,
                              hipStream_t stream) {
  const float* x     = (const float*)d_in[0];
  const float* w_qkv = (const float*)d_in[1];
  const float* w_out = (const float*)d_in[2];
  float* out = (float*)d_out;

  char* ws = (char*)d_ws;
  __bf16* xb    = (__bf16*)(ws);
  __bf16* wqkvb = (__bf16*)(ws + (8ull  << 20));
  __bf16* wob   = (__bf16*)(ws + (14ull << 20));
  __bf16* qkvb  = (__bf16*)(ws + (16ull << 20));
  __bf16* yb    = (__bf16*)(ws + (40ull << 20));

  cvt_f32_bf16<<<2048, 256, 0, stream>>>(x,     xb,    524288);
  cvt_f32_bf16<<<1536, 256, 0, stream>>>(w_qkv, wqkvb, 393216);
  cvt_f32_bf16<<<512,  256, 0, stream>>>(w_out, wob,   131072);
  gemm_bt<1><<<dim3(QKVN / 128, NROWS / 128), 256, 0, stream>>>(xb, wqkvb, qkvb, NROWS, QKVN, EMB);
  attn_causal3<<<1024, 256, 0, stream>>>(qkvb, yb);
  gemm_bt<0><<<dim3(EMB / 128, NROWS / 128), 256, 0, stream>>>(yb, wob, out, NROWS, EMB, EMB);
}

// Round 4
// 115.831 us; speedup vs baseline: 9.0195x; 1.0263x over previous
//
#include <hip/hip_runtime.h>
#include <hip/hip_bf16.h>
#include <cstdint>

// ---------------------------------------------------------------------------
// Fused causal self-attention block (B=2, T=2048, C=1024, H=16, Dh=64), fp32 in/out.
// cvt fp32->bf16 -> QKV GEMM -> V-transpose -> causal flash attn -> out GEMM.
// Workspace (48MB):
//   xb/Vt @ 0     8 MB   bf16 x [4096][1024]; REUSED after gemm1 as Vt [32][64][2048]
//   wqkvb @ 8 MB  6 MB   bf16 w_qkv [3072][1024]
//   wob   @ 14MB  2 MB   bf16 w_out [1024][1024]
//   qkvb  @ 16MB 24 MB   bf16 qkv [4096][3072] (Q|K|V per row)
//   yb    @ 40MB  8 MB   bf16 attn out [4096][1024]
// ---------------------------------------------------------------------------

typedef __bf16 bf16x8 __attribute__((ext_vector_type(8)));
typedef __bf16 bf16x2 __attribute__((ext_vector_type(2)));
typedef float  f32x4  __attribute__((ext_vector_type(4)));

#define EMB   1024
#define HEADS 16
#define HD    64
#define TT    2048
#define NROWS 4096
#define QKVN  3072

// ---- fused fp32 -> bf16 (8 elems / thread, 3 arrays in one launch) ----
__global__ void cvt_all(const float* __restrict__ x, const float* __restrict__ wq,
                        const float* __restrict__ wo, __bf16* __restrict__ xb,
                        __bf16* __restrict__ wqb, __bf16* __restrict__ wob) {
  const int bid = blockIdx.x;
  const float* in; __bf16* out; int i;
  if (bid < 2048)      { in = x;  out = xb;  i = bid * 256 + threadIdx.x; }
  else if (bid < 3584) { in = wq; out = wqb; i = (bid - 2048) * 256 + threadIdx.x; }
  else                 { in = wo; out = wob; i = (bid - 3584) * 256 + threadIdx.x; }
  const float4* p = (const float4*)in + (size_t)i * 2;
  float4 a = p[0], b = p[1];
  bf16x8 o;
  o[0] = (__bf16)a.x; o[1] = (__bf16)a.y; o[2] = (__bf16)a.z; o[3] = (__bf16)a.w;
  o[4] = (__bf16)b.x; o[5] = (__bf16)b.y; o[6] = (__bf16)b.z; o[7] = (__bf16)b.w;
  *((bf16x8*)out + i) = o;
}

__device__ __forceinline__ void gload_lds16(const void* g, void* l) {
  __builtin_amdgcn_global_load_lds(
      (const __attribute__((address_space(1))) void*)(uintptr_t)g,
      (__attribute__((address_space(3))) void*)(uint32_t)(uintptr_t)l,
      16, 0, 0);
}

// ---- GEMM: C[M,N] = A[M,K] * Bm[N,K]^T (m97 structure + XCD swizzle) ----
template <int OUT_BF16>
__global__ __launch_bounds__(256, 2)
void gemm_bt(const __bf16* __restrict__ A, const __bf16* __restrict__ Bm,
             void* __restrict__ Cout, int M, int N, int K) {
  __shared__ __align__(16) __bf16 As[128 * 32];
  __shared__ __align__(16) __bf16 Bs[128 * 32];
  const int tid  = threadIdx.x;
  const int lane = tid & 63;
  const int wid  = tid >> 6;
  const int wr = wid >> 1, wc = wid & 1;
  const int nwg = gridDim.x * gridDim.y;
  int flat = blockIdx.y * gridDim.x + blockIdx.x;
  flat = (flat & 7) * (nwg >> 3) + (flat >> 3);
  const int brow = (flat / gridDim.x) * 128;
  const int bcol = (flat % gridDim.x) * 128;
  const int fr = lane & 15, g = lane >> 4;

  f32x4 acc[4][4];
#pragma unroll
  for (int m = 0; m < 4; m++)
#pragma unroll
    for (int n = 0; n < 4; n++)
#pragma unroll
      for (int r = 0; r < 4; r++) acc[m][n][r] = 0.0f;

  const int c0 = tid, c1 = tid + 256;
  for (int k0 = 0; k0 < K; k0 += 32) {
    __syncthreads();
    gload_lds16(A  + (size_t)(brow + (c0 >> 2)) * K + k0 + (c0 & 3) * 8, (char*)As + c0 * 16);
    gload_lds16(A  + (size_t)(brow + (c1 >> 2)) * K + k0 + (c1 & 3) * 8, (char*)As + c1 * 16);
    gload_lds16(Bm + (size_t)(bcol + (c0 >> 2)) * K + k0 + (c0 & 3) * 8, (char*)Bs + c0 * 16);
    gload_lds16(Bm + (size_t)(bcol + (c1 >> 2)) * K + k0 + (c1 & 3) * 8, (char*)Bs + c1 * 16);
    __syncthreads();

    bf16x8 af[4], bfr[4];
#pragma unroll
    for (int m = 0; m < 4; m++)
      af[m] = *(const bf16x8*)((const char*)As + (wr * 64 + m * 16 + fr) * 64 + g * 16);
#pragma unroll
    for (int n = 0; n < 4; n++)
      bfr[n] = *(const bf16x8*)((const char*)Bs + (wc * 64 + n * 16 + fr) * 64 + g * 16);
#pragma unroll
    for (int m = 0; m < 4; m++)
#pragma unroll
      for (int n = 0; n < 4; n++)
        acc[m][n] = __builtin_amdgcn_mfma_f32_16x16x32_bf16(af[m], bfr[n], acc[m][n], 0, 0, 0);
  }

  const int rbase = brow + wr * 64 + g * 4;
  const int cbase = bcol + wc * 64 + fr;
#pragma unroll
  for (int m = 0; m < 4; m++)
#pragma unroll
    for (int n = 0; n < 4; n++) {
      const int col = cbase + n * 16;
#pragma unroll
      for (int r = 0; r < 4; r++) {
        const int row = rbase + m * 16 + r;
        const float v = acc[m][n][r];
        if (OUT_BF16) ((__bf16*)Cout)[(size_t)row * N + col] = (__bf16)v;
        else          ((float*)Cout)[(size_t)row * N + col]  = v;
      }
    }
}

// ---- V transpose: qkv [4096][3072] (V cols) -> Vt [32 bh][64 d][2048 t] ----
__global__ __launch_bounds__(256)
void vtrans(const __bf16* __restrict__ qkv, __bf16* __restrict__ vt) {
  __shared__ __bf16 tile[64][66];     // pad 66: conflict-light both phases
  const int tt = blockIdx.x;          // t tile (64 rows)
  const int bh = blockIdx.y;
  const int b = bh >> 4, h = bh & 15;
  const int tid = threadIdx.x;
  // load: thread covers V[t0+tl][dq..dq+15]
  const int tl = tid >> 2, dq = (tid & 3) * 16;
  const __bf16* src = qkv + ((size_t)(b * TT + tt * 64 + tl)) * QKVN + 2 * EMB + h * HD + dq;
  bf16x8 v0 = *(const bf16x8*)src;
  bf16x8 v1 = *(const bf16x8*)(src + 8);
#pragma unroll
  for (int u = 0; u < 4; u++) {
    *(bf16x2*)&tile[tl][dq + 2 * u]     = bf16x2{v0[2 * u], v0[2 * u + 1]};
    *(bf16x2*)&tile[tl][dq + 8 + 2 * u] = bf16x2{v1[2 * u], v1[2 * u + 1]};
  }
  __syncthreads();
  // store: thread covers Vt[bh][d][t0 + tc*16 .. +15]
  const int d = tid >> 2, tc = (tid & 3) * 16;
  bf16x8 o0, o1;
#pragma unroll
  for (int j = 0; j < 8; j++) { o0[j] = tile[tc + j][d]; o1[j] = tile[tc + 8 + j][d]; }
  __bf16* dst = vt + ((size_t)bh * HD + d) * TT + tt * 64 + tc;
  *(bf16x8*)dst = o0;
  *(bf16x8*)(dst + 8) = o1;
}

// ---------------------------------------------------------------------------
// Causal flash attention v4: 4 waves/block, wave owns 16 q rows (QBLK=64).
// grid = 1024 (32 chunks x 32 bh). K and Vt both direct gload_lds (source-
// swizzled, linear dest), double-buffered, ONE barrier per tile. exp2-domain
// defer-max softmax; row-sum via ones-MFMA.
// ---------------------------------------------------------------------------
__device__ __forceinline__ int psw(int row) {
  return (((row & 7) ^ ((row >> 3) & 7))) << 4;
}

#define SCL 0.18033688f   /* 0.125 * log2(e) */
#define THR 11.0f         /* defer-max threshold, log2 units */

__global__ __launch_bounds__(256, 4)
void attn_causal4(const __bf16* __restrict__ qkv, const __bf16* __restrict__ vt,
                  __bf16* __restrict__ yb) {
  __shared__ __align__(16) char Kbuf[2][8192];   // K[kv][d], chunk-swizzled
  __shared__ __align__(16) char Vbuf[2][8192];   // Vt[d][kv], chunk-swizzled
  __shared__ __align__(16) char Pbuf[4][2048];   // per-wave P[16][64], psw-swizzled

  const int tid = threadIdx.x;
  const int lane = tid & 63, w = tid >> 6;
  const int L = blockIdx.x;
  const int bh = L & 31, p = L >> 5;
  const int chunk = (p < 16) ? p : 47 - p;       // fold-balanced
  const int b = bh >> 4, h = bh & 15;
  const size_t rowbase = (size_t)b * TT;
  const int q0 = chunk * 64 + w * 16;
  const int fr = lane & 15, g = lane >> 4;
  const int ntiles = chunk + 1;

  bf16x8 qf[2];
#pragma unroll
  for (int kc = 0; kc < 2; kc++)
    qf[kc] = *(const bf16x8*)(qkv + (rowbase + q0 + fr) * QKVN + h * HD + kc * 32 + g * 8);

  bf16x8 ones;
#pragma unroll
  for (int j = 0; j < 8; j++) ones[j] = (__bf16)1.0f;

  f32x4 o[4];
  f32x4 lacc;
  float m[4];
#pragma unroll
  for (int n = 0; n < 4; n++)
#pragma unroll
    for (int r = 0; r < 4; r++) o[n][r] = 0.0f;
#pragma unroll
  for (int r = 0; r < 4; r++) { lacc[r] = 0.0f; m[r] = -1e30f; }

  auto stageK = [&](int kt, int buf) {
#pragma unroll
    for (int i = 0; i < 2; i++) {
      const int c = tid + i * 256;
      const int row = c >> 3;                    // kv-local
      const int c16 = (c & 7) ^ (row & 7);       // source pre-swizzle, linear dest
      gload_lds16(qkv + (rowbase + kt * 64 + row) * QKVN + EMB + h * HD + c16 * 8,
                  Kbuf[buf] + c * 16);
    }
  };
  auto stageV = [&](int kt, int buf) {
#pragma unroll
    for (int i = 0; i < 2; i++) {
      const int c = tid + i * 256;
      const int row = c >> 3;                    // d
      const int c16 = (c & 7) ^ (row & 7);       // kv-chunk pre-swizzle
      gload_lds16(vt + ((size_t)bh * HD + row) * TT + kt * 64 + c16 * 8,
                  Vbuf[buf] + c * 16);
    }
  };

  // prologue
  stageK(0, 0);
  stageV(0, 0);
  __syncthreads();

  int cur = 0;
  for (int kt = 0; kt < ntiles; kt++) {
    if (kt + 1 < ntiles) { stageK(kt + 1, cur ^ 1); stageV(kt + 1, cur ^ 1); }

    const int kv0 = kt * 64;
    // K fragments from swizzled LDS
    bf16x8 kf[4][2];
#pragma unroll
    for (int n = 0; n < 4; n++)
#pragma unroll
      for (int kc = 0; kc < 2; kc++) {
        const int row = n * 16 + fr;
        kf[n][kc] = *(const bf16x8*)(Kbuf[cur] + row * 128 + (((kc << 2) | g) ^ (row & 7)) * 16);
      }
    // S = Q K^T
    f32x4 s[4];
#pragma unroll
    for (int n = 0; n < 4; n++) {
#pragma unroll
      for (int r = 0; r < 4; r++) s[n][r] = 0.0f;
#pragma unroll
      for (int kc = 0; kc < 2; kc++)
        s[n] = __builtin_amdgcn_mfma_f32_16x16x32_bf16(qf[kc], kf[n][kc], s[n], 0, 0, 0);
    }
    // scale (log2 domain) + causal mask on the diagonal tile
    if (kt == chunk) {
#pragma unroll
      for (int n = 0; n < 4; n++)
#pragma unroll
        for (int r = 0; r < 4; r++) {
          const float val = s[n][r] * SCL;
          const int qg = q0 + g * 4 + r;
          const int kg = kv0 + n * 16 + fr;
          s[n][r] = (kg > qg) ? -1e30f : val;
        }
    } else {
#pragma unroll
      for (int n = 0; n < 4; n++)
#pragma unroll
        for (int r = 0; r < 4; r++) s[n][r] *= SCL;
    }
    // defer-max vote softmax
    float pm[4];
#pragma unroll
    for (int r = 0; r < 4; r++)
      pm[r] = fmaxf(fmaxf(s[0][r], s[1][r]), fmaxf(s[2][r], s[3][r]));
    const bool ok = (pm[0] <= m[0] + THR) && (pm[1] <= m[1] + THR) &&
                    (pm[2] <= m[2] + THR) && (pm[3] <= m[3] + THR);
    if (!__all(ok)) {
#pragma unroll
      for (int r = 0; r < 4; r++) {
        float rm = pm[r];
#pragma unroll
        for (int d = 1; d < 16; d <<= 1) rm = fmaxf(rm, __shfl_xor(rm, d, 16));
        const float nm = fmaxf(m[r], rm);
        const float f = exp2f(m[r] - nm);
        m[r] = nm;
        lacc[r] *= f;
#pragma unroll
        for (int n = 0; n < 4; n++) o[n][r] *= f;
      }
    }
    // P = exp2(S - m) -> wave-private LDS (bf16, swizzled)
#pragma unroll
    for (int n = 0; n < 4; n++)
#pragma unroll
      for (int r = 0; r < 4; r++) {
        const float e = exp2f(s[n][r] - m[r]);
        const int row = g * 4 + r;
        *(__bf16*)(Pbuf[w] + row * 128 + (((n * 16 + fr) * 2) ^ psw(row))) = (__bf16)e;
      }
    // PV + row-sum via ones-MFMA
    bf16x8 pa[2];
#pragma unroll
    for (int kc = 0; kc < 2; kc++)
      pa[kc] = *(const bf16x8*)(Pbuf[w] + fr * 128 + ((kc * 64 + g * 16) ^ psw(fr)));
    bf16x8 vb[4][2];
#pragma unroll
    for (int n = 0; n < 4; n++)
#pragma unroll
      for (int kc = 0; kc < 2; kc++) {
        const int row = n * 16 + fr;             // d
        vb[n][kc] = *(const bf16x8*)(Vbuf[cur] + row * 128 + (((kc << 2) | g) ^ (row & 7)) * 16);
      }
#pragma unroll
    for (int kc = 0; kc < 2; kc++) {
      lacc = __builtin_amdgcn_mfma_f32_16x16x32_bf16(pa[kc], ones, lacc, 0, 0, 0);
#pragma unroll
      for (int n = 0; n < 4; n++)
        o[n] = __builtin_amdgcn_mfma_f32_16x16x32_bf16(pa[kc], vb[n][kc], o[n], 0, 0, 0);
    }

    __syncthreads();   // waves done with cur; next tile's DMA drained
    cur ^= 1;
  }

  // normalize + store
#pragma unroll
  for (int n = 0; n < 4; n++)
#pragma unroll
    for (int r = 0; r < 4; r++) {
      const int q = q0 + g * 4 + r;
      const int d = n * 16 + fr;
      yb[(rowbase + q) * EMB + h * HD + d] = (__bf16)(o[n][r] / lacc[r]);
    }
}

extern "C" void kernel_launch(void* const* d_in, const int* in_sizes, int n_in,
                              void* d_out, int out_size, void* d_ws, size_t ws_size,
                              hipStream_t stream) {
  const float* x     = (const float*)d_in[0];
  const float* w_qkv = (const float*)d_in[1];
  const float* w_out = (const float*)d_in[2];
  float* out = (float*)d_out;

  char* ws = (char*)d_ws;
  __bf16* xb    = (__bf16*)(ws);                 // reused as Vt after gemm1
  __bf16* wqkvb = (__bf16*)(ws + (8ull  << 20));
  __bf16* wob   = (__bf16*)(ws + (14ull << 20));
  __bf16* qkvb  = (__bf16*)(ws + (16ull << 20));
  __bf16* yb    = (__bf16*)(ws + (40ull << 20));
  __bf16* vtb   = xb;

  cvt_all<<<4096, 256, 0, stream>>>(x, w_qkv, w_out, xb, wqkvb, wob);
  gemm_bt<1><<<dim3(QKVN / 128, NROWS / 128), 256, 0, stream>>>(xb, wqkvb, qkvb, NROWS, QKVN, EMB);
  vtrans<<<dim3(TT / 64, 32), 256, 0, stream>>>(qkvb, vtb);
  attn_causal4<<<1024, 256, 0, stream>>>(qkvb, vtb, yb);
  gemm_bt<0><<<dim3(EMB / 128, NROWS / 128), 256, 0, stream>>>(yb, wob, out, NROWS, EMB, EMB);
}